// Round 6
// baseline (435.927 us; speedup 1.0000x reference)
//
#include <hip/hip_runtime.h>

#define LL 128
#define STR 135            // odd, ≡7 (mod 32): strided streams <=2-way; i*(STR+1)+2m is 8B-aligned
#define STR1 136           // STR+1
#define NT 1024
#define LARGENEG -1.0e30f

__device__ __forceinline__ float softplus_f(float x) { return log1pf(__expf(x)); }
__device__ __forceinline__ float sigmoid_f(float x) { return 1.0f / (1.0f + __expf(-x)); }

// LDS layout:
//   Al[r*STR+c], c>=r : A[r][c]       (inside values incl. diagonal)
//   Al[r*STR+c], c< r : A[c][r]       (A transposed -> row-contiguous column reads)
//   Gl[r*STR+c], c>=r : left-acc for child (r,c)   [diag slot = left-acc for (r,r)]
//   Gl[r*STR+c], c< r : right-acc for child (c,r)  (transposed)
//   DR[r]             : right-acc for diagonal child (r,r)
// S is NOT stored: S[i,j] = A[i,j] - softplus(s_ij), recomputed in the outside pass.
extern "C" __global__ __launch_bounds__(NT, 1) void cky_kernel(
    const float* __restrict__ scores,
    const int* __restrict__ seq_lens,
    float* __restrict__ Z_out,
    float* __restrict__ marg_out)
{
    extern __shared__ float smem[];
    float* Al = smem;
    float* Gl = smem + LL * STR;
    float* DR = smem + 2 * LL * STR;

    const int b   = blockIdx.x;
    const int tid = threadIdx.x;
    const float* s = scores + (size_t)b * LL * LL;
    float* marg = marg_out + (size_t)b * LL * LL;
    const int len = seq_lens[b];   // DP truncated to len (outside gradients are exactly 0)

    for (int idx = tid; idx < LL * LL; idx += NT) marg[idx] = 0.0f;
    for (int idx = tid; idx < LL * STR; idx += NT) Gl[idx] = 0.0f;
    if (tid < LL) DR[tid] = 0.0f;

    // Width 0 diagonal (A and A^T share the diagonal slot).
    if (tid < len) Al[tid * STR + tid] = softplus_f(s[tid * LL + tid]);
    __syncthreads();

    // ---------------- Inside pass (single-pass LSE, shift M = A[i][j-1]) ----
    // M = A[i][j-1] is a lower bound of max_k v_k via k=j-1 (v_{j-1} = M + A[j][j] >= M)
    // so sum >= exp(A[j][j]) >= 1 (no log(0)); spread above M is O(10) for N(0,1)
    // scores -> no overflow (margin to 88).
    for (int w = 1; w < len; ++w) {
        const int cells = len - w;
        const int cl  = (cells > 1) ? (32 - __clz(cells - 1)) : 0;
        int gsh = 10 - cl; if (gsh > 6) gsh = 6;       // cells * 2^gsh <= 1024
        const int g    = 1 << gsh;
        const int gid  = tid >> gsh;
        const int lane = tid & (g - 1);
        if (gid < cells) {
            const int i = gid, j = gid + w;
            const float sv = s[i * LL + j];                 // prefetch, overlaps k-walk
            const float M  = Al[i * STR + (j - 1)];
            const float* Arow  = Al + i * STR1;             // A[i][i+e] at [e]; even e -> 8B-aligned
            const float* ATrow = Al + j * STR + i + 1;      // A[i+e+1][j] at [e]
            float acc = 0.0f;
            const int m2 = 2 * lane;
            #pragma unroll
            for (int t = 0; t < 4; ++t) {
                if (2 * g * t < w) {                        // wave-uniform trip guard
                    const int e = m2 + 2 * g * t;
                    float2 a2 = *(const float2*)(Arow + e); // speculative, masked below
                    float at0 = ATrow[e];
                    float at1 = ATrow[e + 1];
                    float e0 = __expf(a2.x + at0 - M);
                    float e1 = __expf(a2.y + at1 - M);
                    acc += (e     < w) ? e0 : 0.0f;         // garbage/NaN discarded by select
                    acc += (e + 1 < w) ? e1 : 0.0f;
                }
            }
            for (int off = g >> 1; off; off >>= 1)
                acc += __shfl_xor(acc, off, 64);
            if (lane == 0) {
                const float Aij = M + __logf(acc) + softplus_f(sv);
                Al[i * STR + j] = Aij;                      // A
                Al[j * STR + i] = Aij;                      // A^T
            }
        }
        __syncthreads();
    }

    if (tid == 0) Z_out[b] = Al[0 * STR + (len - 1)];

    // ---------------- Outside pass (race-free paired scatter) ---------------
    // Parent (i,J): t_k = exp(A[i,k] + A[k+1,J] - (S[i,J] - log G[i,J])), arg <= 0.
    //   left child (i,k)    -> Gl[i*STR+k]   (k==i hits Gl diag: unique writer/phase)
    //   right child (k+1,J) -> Gl[J*STR+k+1] (k+1==J peeled to DR[J])
    for (int w = len - 1; w >= 1; --w) {
        const int cells = len - w;
        const int cl  = (cells > 1) ? (32 - __clz(cells - 1)) : 0;
        int gsh = 10 - cl; if (gsh > 6) gsh = 6;
        const int g    = 1 << gsh;
        const int gid  = tid >> gsh;
        const int lane = tid & (g - 1);
        if (gid < cells) {
            const int i = gid, J = i + w;
            const float sv = s[i * LL + J];
            float Gp = Gl[i * STR + J] + Gl[J * STR + i];   // finalized at this phase
            if (i == 0 && J == len - 1) Gp += 1.0f;         // seed dZ/dA[0][len-1]
            if (lane == 0)
                marg[i * LL + J] = Gp * sigmoid_f(sv);
            if (Gp > 0.0f) {
                const float SL = Al[i * STR + J] - softplus_f(sv) - __logf(Gp);
                const float* Arow  = Al + i * STR1;
                const float* ATrow = Al + J * STR + i + 1;
                float*       Lrow  = Gl + i * STR1;         // left-acc; e=0 is the diag slot
                float*       Rrow  = Gl + J * STR + i + 1;  // right-acc row J
                const int bulk = w - 1;                     // edges e in [0, w-1); e=w-1 peeled
                const int m2 = 2 * lane;
                #pragma unroll
                for (int t = 0; t < 4; ++t) {
                    if ((t + 1) * 2 * g <= bulk) {          // wave-uniform full trip
                        const int e = m2 + 2 * g * t;
                        float2 a2 = *(const float2*)(Arow + e);
                        float t0 = __expf(a2.x + ATrow[e]     - SL);
                        float t1 = __expf(a2.y + ATrow[e + 1] - SL);
                        float2 l2 = *(const float2*)(Lrow + e);
                        l2.x += t0; l2.y += t1;
                        *(float2*)(Lrow + e) = l2;
                        Rrow[e]     += t0;
                        Rrow[e + 1] += t1;
                    }
                }
                const int e0 = (bulk / (2 * g)) * (2 * g);  // remainder edges
                for (int e = e0 + lane; e < bulk; e += g) {
                    float tt = __expf(Arow[e] + ATrow[e] - SL);
                    Lrow[e] += tt;
                    Rrow[e] += tt;
                }
                if (lane == 0) {                            // final edge k = J-1
                    float tt = __expf(Arow[w - 1] + Al[J * STR + J] - SL);
                    Lrow[w - 1] += tt;
                    DR[J]       += tt;
                }
            }
        }
        __syncthreads();
    }

    // Width-0 cells: G[i][i] = left-diag (Gl diag) + right-diag (DR).
    if (tid < len)
        marg[tid * LL + tid] = (Gl[tid * STR + tid] + DR[tid]) * sigmoid_f(s[tid * LL + tid]);
}

extern "C" void kernel_launch(void* const* d_in, const int* in_sizes, int n_in,
                              void* d_out, int out_size, void* d_ws, size_t ws_size,
                              hipStream_t stream) {
    const float* scores  = (const float*)d_in[0];
    const int* seq_lens  = (const int*)d_in[1];
    const int B = in_sizes[1];              // 32
    float* out = (float*)d_out;
    float* Z_out = out;                     // B floats
    float* marg  = out + B;                 // B*L*L floats

    const size_t lds_bytes = (size_t)(2 * LL * STR + 2 * LL) * sizeof(float);  // 139264 B
    hipFuncSetAttribute((const void*)cky_kernel,
                        hipFuncAttributeMaxDynamicSharedMemorySize,
                        (int)lds_bytes);
    cky_kernel<<<B, NT, lds_bytes, stream>>>(scores, seq_lens, Z_out, marg);
}

// Round 7
// 323.462 us; speedup vs baseline: 1.3477x; 1.3477x over previous
//
#include <hip/hip_runtime.h>

#define LL 128
#define STR 135            // odd, ≡7 (mod 32): strided column streams conflict-free
#define STR1 136           // STR+1 (even): row bases 8B-aligned for float2
#define NT 1024

__device__ __forceinline__ float softplus_f(float x) { return log1pf(__expf(x)); }

// LDS layout:
//   Al[r*STR+c], c>=r : A[r][c]     (inside values incl. diagonal)
//   Al[r*STR+c], c< r : S[c][r]     (pre-softplus LSE, transposed; width>=1)
//   Gl[r*STR+c], c>=r : left-acc for child (r,c)   [diag slot = left-acc (r,r)]
//   Gl[r*STR+c], c< r : right-acc for child (c,r)  (transposed)
//   DR[r]             : right-acc for diagonal child (r,r)
// No global loads/stores inside the outside phase loop; marg written in epilogue.
extern "C" __global__ __launch_bounds__(NT, 1) void cky_kernel(
    const float* __restrict__ scores,
    const int* __restrict__ seq_lens,
    float* __restrict__ Z_out,
    float* __restrict__ marg_out)
{
    extern __shared__ float smem[];
    float* Al = smem;
    float* Gl = smem + LL * STR;
    float* DR = smem + 2 * LL * STR;

    const int b   = blockIdx.x;
    const int tid = threadIdx.x;
    const float* s = scores + (size_t)b * LL * LL;
    float* marg = marg_out + (size_t)b * LL * LL;
    const int len = seq_lens[b];

    for (int idx = tid; idx < LL * STR; idx += NT) Gl[idx] = 0.0f;
    if (tid < LL) DR[tid] = 0.0f;
    if (tid < len) Al[tid * STR + tid] = softplus_f(s[tid * LL + tid]);
    __syncthreads();

    // ---------------- Inside pass (single-pass LSE, shift M = A[i][j-1]) ----
    for (int w = 1; w < len; ++w) {
        const int cells = len - w;
        const int clw = (w > 1) ? (32 - __clz(w - 1)) : 0;        // ceil(log2 w)
        const int clc = (cells > 1) ? (32 - __clz(cells - 1)) : 0;
        int gsh = clw - 3; if (gsh < 0) gsh = 0;                   // g >= w/8 -> <=4 float2 trips
        int cap = 10 - clc; if (gsh > cap) gsh = cap;              // cells * g <= NT (always feasible)
        if (gsh > 6) gsh = 6;
        const int g    = 1 << gsh;
        const int gid  = tid >> gsh;
        const int lane = tid & (g - 1);
        if (gid < cells) {
            const int i = gid, j = gid + w;
            const float sv = s[i * LL + j];                 // only global op; overlapped
            const float M  = Al[i * STR + (j - 1)];         // LSE shift (lower bound of max)
            const float* Arow = Al + i * STR1;              // A[i][i+e]
            const float* Acol = Al + (i + 1) * STR + j;     // A[i+1+e][j] at [e*STR]
            float acc = 0.0f;
            const int m2 = 2 * lane;
            #pragma unroll
            for (int t = 0; t < 4; ++t) {
                if (2 * g * t < w) {                        // wave-uniform trip guard
                    const int e = m2 + 2 * g * t;
                    float2 a2 = *(const float2*)(Arow + e); // speculative; masked below
                    float c0 = Acol[e * STR];
                    float c1 = Acol[(e + 1) * STR];
                    float e0 = __expf(a2.x + c0 - M);
                    float e1 = __expf(a2.y + c1 - M);
                    acc += (e     < w) ? e0 : 0.0f;         // garbage/NaN discarded by select
                    acc += (e + 1 < w) ? e1 : 0.0f;
                }
            }
            for (int off = g >> 1; off; off >>= 1)
                acc += __shfl_xor(acc, off, 64);
            if (lane == 0) {
                const float Sij = M + __logf(acc);          // sum >= exp(A[j][j]) >= 1
                Al[j * STR + i] = Sij;                      // S^T
                Al[i * STR + j] = Sij + softplus_f(sv);     // A
            }
        }
        __syncthreads();
    }

    // ---------------- Outside pass (race-free paired scatter, LDS-only) -----
    // Parent (i,J): t_e = exp(A[i,i+e] + A[i+e+1,J] - (S[i,J] - log G[i,J])) <= 1.
    //   left child (i,i+e)    -> Gl[i*STR+(i+e)]  (e=0 hits the diag slot)
    //   right child (i+e+1,J) -> Gl[J*STR+(i+e+1)] (e=w-1 peeled to DR[J])
    for (int w = len - 1; w >= 1; --w) {
        const int cells = len - w;
        const int clw = (w > 1) ? (32 - __clz(w - 1)) : 0;
        const int clc = (cells > 1) ? (32 - __clz(cells - 1)) : 0;
        int gsh = clw - 3; if (gsh < 0) gsh = 0;
        int cap = 10 - clc; if (gsh > cap) gsh = cap;
        if (gsh > 6) gsh = 6;
        const int g    = 1 << gsh;
        const int gid  = tid >> gsh;
        const int lane = tid & (g - 1);
        if (gid < cells) {
            const int i = gid, J = i + w;
            float Gp = Gl[i * STR + J] + Gl[J * STR + i];   // finalized at this phase
            if (i == 0 && J == len - 1) Gp += 1.0f;         // root seed
            if (Gp > 0.0f) {
                const float SL = Al[J * STR + i] - __logf(Gp);   // S[i,J] - log Gp (from LDS)
                const float* Arow = Al + i * STR1;
                const float* Acol = Al + (i + 1) * STR + J;
                float*       Lrow = Gl + i * STR1;          // left-acc row i (e=0 = diag slot)
                float*       Rrow = Gl + J * STR + i + 1;   // right-acc row J
                const int bulk = w - 1;                     // e in [0, w-1); e=w-1 peeled
                const int m2 = 2 * lane;
                #pragma unroll
                for (int t = 0; t < 4; ++t) {
                    if ((t + 1) * 2 * g <= bulk) {          // wave-uniform FULL trips only
                        const int e = m2 + 2 * g * t;
                        float2 a2 = *(const float2*)(Arow + e);
                        float t0 = __expf(a2.x + Acol[e * STR]       - SL);
                        float t1 = __expf(a2.y + Acol[(e + 1) * STR] - SL);
                        float2 l2 = *(const float2*)(Lrow + e);
                        l2.x += t0; l2.y += t1;
                        *(float2*)(Lrow + e) = l2;
                        float r0 = Rrow[e] + t0;            // scalar: base parity varies
                        float r1 = Rrow[e + 1] + t1;
                        Rrow[e] = r0; Rrow[e + 1] = r1;
                    }
                }
                const int e0 = (bulk / (2 * g)) * (2 * g);  // remainder edges
                for (int e = e0 + lane; e < bulk; e += g) {
                    float tt = __expf(Arow[e] + Acol[e * STR] - SL);
                    Lrow[e] += tt;
                    Rrow[e] += tt;
                }
                if (lane == 0) {                            // final edge e = w-1 (right child = (J,J))
                    float tt = __expf(Arow[w - 1] + Al[J * STR + J] - SL);
                    Lrow[w - 1] += tt;
                    DR[J]       += tt;
                }
            }
        }
        __syncthreads();
    }

    // ---------------- Epilogue: marg + Z, coalesced ----------------
    if (tid == 0) Z_out[b] = Al[0 * STR + (len - 1)];
    for (int idx = tid; idx < LL * LL; idx += NT) {
        const int r = idx >> 7, c = idx & (LL - 1);
        float G = 0.0f;
        if (c < len) {
            if (c > r)       G = Gl[r * STR + c] + Gl[c * STR + r];
            else if (c == r) G = Gl[r * STR + r] + DR[r];
            if (r == 0 && c == len - 1) G += 1.0f;          // root
        }
        float m = 0.0f;
        if (G != 0.0f) {
            const float sv = s[idx];
            m = G / (1.0f + __expf(-sv));                   // G * sigmoid(s)
        }
        marg[idx] = m;
    }
}

extern "C" void kernel_launch(void* const* d_in, const int* in_sizes, int n_in,
                              void* d_out, int out_size, void* d_ws, size_t ws_size,
                              hipStream_t stream) {
    const float* scores  = (const float*)d_in[0];
    const int* seq_lens  = (const int*)d_in[1];
    const int B = in_sizes[1];              // 32
    float* out = (float*)d_out;
    float* Z_out = out;                     // B floats
    float* marg  = out + B;                 // B*L*L floats

    const size_t lds_bytes = (size_t)(2 * LL * STR + LL) * sizeof(float);  // 138752 B
    hipFuncSetAttribute((const void*)cky_kernel,
                        hipFuncAttributeMaxDynamicSharedMemorySize,
                        (int)lds_bytes);
    cky_kernel<<<B, NT, lds_bytes, stream>>>(scores, seq_lens, Z_out, marg);
}